// Round 5
// baseline (1947.074 us; speedup 1.0000x reference)
//
#include <hip/hip_runtime.h>
#include <hip/hip_cooperative_groups.h>
#include <math.h>

namespace cg = cooperative_groups;

// RealNVP, 8 layers, B=262144, H=128, scalar coupling input.
// Exact piecewise-linear collapse (verified R4), now fused into a SINGLE
// cooperative kernel: one thread per sample, state (x0,x1,sldj,bin) lives in
// registers across layers; grid.sync() replaces 33 kernel boundaries that
// dominated R4's 648 us (dispatch overhead ~8-13 us each, work is tiny).
// Stats via per-block partials (no atomics, poison-safe); bins zeroed by an
// idle block in the prep phase.

#define BN_ 262144
#define H_ 128
#define NBINS 129
#define NBLK 256
#define NTHR 1024

// ws layout (float offsets)
#define OFF_PART 0                       // double2 parts[2][256] = 2048 floats
#define OFF_BIN  2048                    // 512 (cnt[0..131], sx[+132], sxx[+264])
#define OFF_TS   2560                    // 128 sorted breakpoints
#define OFF_S    2688                    // float2 S[129][128]
#define OFF_XS   (OFF_S + 2*NBINS*H_)    // crossings, 129 rows stride 132
#define OFF_SEG  (OFF_XS + NBINS*132)    // float4 seg[129][132]
#define OFF_REF  (OFF_SEG + NBINS*132*4) // float ref[129][132]
#define OFF_CNT  (OFF_REF + NBINS*132)   // 129 ints

struct SmemPrep {
    float sA[H_], sC[H_], sT[H_], vrow[H_];
    int order[H_];
    double2 scan2[H_];
    double red[16];
};
struct SmemHist {
    float lts[H_];
    float lb[4 * 396];
};
struct SmemFin {
    float xcS[H_], xsS[H_];
    double2 dS[H_];
    double red[16];
};
struct SmemApply {
    double red[32];
};
union Smem { SmemPrep p; SmemHist h; SmemFin f; SmemApply a; };

// 1024-thread block sum; leading barrier protects tmp reuse across calls.
__device__ __forceinline__ double bred1024(double v, volatile double* tmp, int tid) {
    for (int off = 32; off; off >>= 1) v += __shfl_down(v, off);
    __syncthreads();
    if ((tid & 63) == 0) tmp[tid >> 6] = v;
    __syncthreads();
    double r = 0.0;
    #pragma unroll
    for (int w = 0; w < 16; w++) r += tmp[w];
    return r;
}

__global__ __launch_bounds__(NTHR, 1) void k_fused(
    const float* __restrict__ x,
    const float* __restrict__ v1, const float* __restrict__ g1,
    const float* __restrict__ bn1g, const float* __restrict__ bn1b,
    const float* __restrict__ v2, const float* __restrict__ g2,
    const float* __restrict__ b2,
    const float* __restrict__ bn2g, const float* __restrict__ bn2b,
    const float* __restrict__ wf, const float* __restrict__ bf,
    float* __restrict__ ws, float* __restrict__ out) {

    cg::grid_group grid = cg::this_grid();
    __shared__ Smem sm;
    const int tid = threadIdx.x;
    const int blk = blockIdx.x;
    const int b = blk * NTHR + tid;
    double2* parts = (double2*)(ws + OFF_PART);

    float2 xv = ((const float2*)x)[b];
    float x0v = xv.x, x1v = xv.y, sl = 0.f;

    { // init: block-partial stats of x1 (layer 0's xin) -> parts[0][blk]
        double s1 = x1v, s2 = (double)x1v * x1v;
        for (int off = 32; off; off >>= 1) { s1 += __shfl_down(s1, off); s2 += __shfl_down(s2, off); }
        if ((tid & 63) == 0) { sm.a.red[tid >> 6] = s1; sm.a.red[16 + (tid >> 6)] = s2; }
        __syncthreads();
        if (tid == 0) {
            double a = 0, c = 0;
            for (int w = 0; w < 16; w++) { a += sm.a.red[w]; c += sm.a.red[16 + w]; }
            parts[blk] = make_double2(a, c);
        }
    }
    grid.sync();

    int bin = 0;
    for (int l = 0; l < 8; ++l) {
        const int par = l & 1;
        const int rev = (l & 1) ^ 1;   // rev=1 for even layers

        // ---- PREP: blocks 0..127 build S-table column i=blk; block 128 zeros bins ----
        if (blk < H_) {
            const int i = blk, j = tid;
            double ps1 = 0, ps2 = 0;
            if (tid < NBLK) { double2 p = parts[par*NBLK + tid]; ps1 = p.x; ps2 = p.y; }
            double Ssum = bred1024(ps1, sm.p.red, tid);
            double SSq  = bred1024(ps2, sm.p.red, tid);
            double mx = Ssum * (1.0 / BN_);
            double vx = fmax(SSq * (1.0 / BN_) - mx * mx, 0.0);

            float a = 0.f, c = 0.f, tj = INFINITY;
            int rk = 0;
            if (j < H_) {
                float g1v = g1[l*H_ + j];
                float w1 = (v1[l*H_ + j] >= 0.f) ? g1v : -g1v;
                double rr = 1.0 / sqrt(vx * (double)g1v * g1v + 1e-5);
                a = (float)((double)w1 * rr * bn1g[l*H_ + j]);
                c = (float)((double)bn1b[l*H_ + j] - mx * a);
                tj = (a != 0.f) ? (float)(-(double)c / a) : INFINITY;
                sm.p.sA[j] = a; sm.p.sC[j] = c; sm.p.sT[j] = tj;
            }
            __syncthreads();
            if (j < H_) {
                for (int q = 0; q < H_; q++) {
                    float tq = sm.p.sT[q];
                    rk += ((tq < tj) || (tq == tj && q < j)) ? 1 : 0;
                }
                sm.p.order[rk] = j;
            }
            float vv = 0.f;
            if (j < H_) { vv = v2[l*H_*H_ + i*H_ + j]; sm.p.vrow[j] = vv; }
            double n2 = bred1024((double)vv * vv, sm.p.red, tid);
            double wsc = (double)g2[l*H_ + i] / sqrt(n2);
            bool bm = (j < H_) && ((a < 0.f) || (a == 0.f && c > 0.f));
            double base1 = bred1024(bm ? wsc * vv * a : 0.0, sm.p.red, tid);
            double base0 = bred1024(bm ? wsc * vv * c : 0.0, sm.p.red, tid);

            if (j < H_) {
                int jj = sm.p.order[j];
                float aa = sm.p.sA[jj], cc = sm.p.sC[jj], vj = sm.p.vrow[jj];
                double d1 = 0.0, d0 = 0.0;
                if (aa != 0.f) {
                    double sg = (aa > 0.f) ? 1.0 : -1.0;
                    double wj = wsc * vj;
                    d1 = sg * wj * aa; d0 = sg * wj * cc;
                }
                sm.p.scan2[j] = make_double2(d1, d0);
            }
            __syncthreads();
            for (int off = 1; off < H_; off <<= 1) {
                double2 add = make_double2(0.0, 0.0);
                if (j >= off && j < H_) add = sm.p.scan2[j - off];
                __syncthreads();
                if (j < H_) { sm.p.scan2[j].x += add.x; sm.p.scan2[j].y += add.y; }
                __syncthreads();
            }
            if (j < H_) {
                double b2i = b2[l*H_ + i];
                float2* S = (float2*)(ws + OFF_S);
                double2 sj = sm.p.scan2[j];
                S[(j + 1)*H_ + i] = make_float2((float)(base1 + sj.x), (float)(base0 + sj.y + b2i));
                if (j == 0) S[i] = make_float2((float)base1, (float)(base0 + b2i));
                if (i == 0) ws[OFF_TS + rk] = tj;   // sorted breakpoints
            }
        } else if (blk == H_) {
            if (tid < 512) ws[OFF_BIN + tid] = 0.f;
        }
        grid.sync();

        // ---- HIST: every thread bins its sample; LDS hist -> global atomics ----
        {
            if (tid < H_) sm.h.lts[tid] = ws[OFF_TS + tid];
            for (int e = tid; e < 4 * 396; e += NTHR) sm.h.lb[e] = 0.f;
            __syncthreads();
            float xin = rev ? x1v : x0v;
            int lo = 0, hi = H_;
            while (lo < hi) {                  // lower_bound: bin = #{t < x}
                int mid = (lo + hi) >> 1;
                if (sm.h.lts[mid] < xin) lo = mid + 1; else hi = mid;
            }
            bin = lo;
            float* lbr = sm.h.lb + ((tid >> 6) & 3) * 396;
            atomicAdd(&lbr[bin], 1.f);
            atomicAdd(&lbr[132 + bin], xin);
            atomicAdd(&lbr[264 + bin], xin * xin);
            __syncthreads();
            for (int e = tid; e < 396; e += NTHR) {
                float v = sm.h.lb[e] + sm.h.lb[396 + e] + sm.h.lb[792 + e] + sm.h.lb[1188 + e];
                atomicAdd(&ws[OFF_BIN + e], v);
            }
        }
        grid.sync();

        // ---- FIN: blocks 0..128 -> exact BN2 stats + segment tables ----
        if (blk < NBINS) {
            const int i = tid, k = blk;
            const float2* S = (const float2*)(ws + OFF_S);
            const float* bins = ws + OFF_BIN;
            const float* ts = ws + OFF_TS;
            float F1 = 0.f, F0 = 0.f, xc = INFINITY;
            bool act = false, has = false;
            if (i < H_) {
                double M = 0.0, E = 0.0;
                for (int kk = 0; kk < NBINS; ++kk) {
                    float2 s = S[kk*H_ + i];
                    double cn = bins[kk], sx = bins[132 + kk], sxx = bins[264 + kk];
                    M += (double)s.x * sx + (double)s.y * cn;
                    E += (double)s.x * ((double)s.x * sxx + 2.0 * s.y * sx) + (double)s.y * s.y * cn;
                }
                double mean = M * (1.0 / BN_);
                double var = fmax(E * (1.0 / BN_) - mean * mean, 0.0);
                double R = (double)bn2g[l*H_ + i] / sqrt(var + 1e-5);
                float2 sk = S[k*H_ + i];
                F1 = (float)((double)sk.x * R);
                F0 = (float)(((double)sk.y - mean) * R + bn2b[l*H_ + i]);
                float lo_ = (k == 0) ? -3.0e38f : ts[k - 1];
                float hi_ = (k == NBINS - 1) ? 3.0e38f : ts[k];
                double hlo = (double)F1 * lo_ + F0;
                act = (k == 0) ? ((F1 < 0.f) || (F1 == 0.f && F0 > 0.f))
                               : ((hlo > 0.0) || (hlo == 0.0 && F1 > 0.f));
                if (F1 != 0.f) {
                    double td = -(double)F0 / F1;
                    if (td > lo_ && td < hi_) { has = true; xc = (float)td; }
                }
                sm.f.xcS[i] = xc;
            }
            __syncthreads();
            int r = 0;
            if (i < H_) {
                for (int q = 0; q < H_; ++q) {
                    float key = sm.f.xcS[q];
                    r += ((key < xc) || (key == xc && q < i)) ? 1 : 0;
                }
            }
            double cntd = bred1024(has ? 1.0 : 0.0, sm.f.red, tid);
            int cnt = (int)(cntd + 0.5);
            float wfs = 0.f, wft = 0.f;
            if (i < H_) { wfs = wf[l*2*H_ + i]; wft = wf[l*2*H_ + H_ + i]; }
            if (has) {
                double sg = (F1 > 0.f) ? 1.0 : -1.0;
                sm.f.dS[r] = make_double2(sg * (double)wfs * F1, sg * (double)wft * F1);
                sm.f.xsS[r] = xc;
                ws[OFF_XS + k*132 + r] = xc;
            }
            __syncthreads();
            float ref0 = (k == 0) ? ((cnt > 0) ? sm.f.xsS[0] : ts[0]) : ts[k - 1];
            float hr = 0.f;
            if (i < H_) hr = fmaxf(fmaf(F1, ref0, F0), 0.f);
            double Vs0 = bred1024((double)wfs * hr, sm.f.red, tid);
            double Vt0 = bred1024((double)wft * hr, sm.f.red, tid);
            double As0 = bred1024(act ? (double)wfs * F1 : 0.0, sm.f.red, tid);
            double At0 = bred1024(act ? (double)wft * F1 : 0.0, sm.f.red, tid);
            if (tid == 0) {
                float4* seg = (float4*)(ws + OFF_SEG) + k * 132;
                float* refk = ws + OFF_REF + k * 132;
                double As = As0, At = At0;
                double Vs = Vs0 + bf[2*l], Vt = Vt0 + bf[2*l + 1];
                float ref = ref0;
                seg[0] = make_float4((float)As, (float)Vs, (float)At, (float)Vt);
                refk[0] = ref;
                for (int r2 = 0; r2 < cnt; ++r2) {
                    float xr = sm.f.xsS[r2];
                    Vs += As * (double)(xr - ref);
                    Vt += At * (double)(xr - ref);
                    As += sm.f.dS[r2].x; At += sm.f.dS[r2].y;
                    ref = xr;
                    seg[r2 + 1] = make_float4((float)As, (float)Vs, (float)At, (float)Vt);
                    refk[r2 + 1] = ref;
                }
                ((int*)ws)[OFF_CNT + k] = cnt;
            }
        }
        grid.sync();

        // ---- APPLY: per-thread segment lookup + point-slope eval + coupling ----
        {
            float xin = rev ? x1v : x0v;
            float xo  = rev ? x0v : x1v;
            int cnt = ((const int*)ws)[OFF_CNT + bin];
            const float* xsk = ws + OFF_XS + bin * 132;
            int r = 0;
            while (r < cnt && xin > xsk[r]) ++r;
            float4 rec = ((const float4*)(ws + OFF_SEG))[bin * 132 + r];
            float ref = ws[OFF_REF + bin * 132 + r];
            float dx = xin - ref;
            float st_s = fmaf(rec.x, dx, rec.y);
            float st_t = fmaf(rec.z, dx, rec.w);
            float s = tanhf(st_s);
            float y = expf(s) * xo + st_t;
            sl += s;
            if (l < 7) {
                if (rev) x0v = y; else x1v = y;
                double s1 = y, s2 = (double)y * y;
                for (int off = 32; off; off >>= 1) { s1 += __shfl_down(s1, off); s2 += __shfl_down(s2, off); }
                __syncthreads();
                if ((tid & 63) == 0) { sm.a.red[tid >> 6] = s1; sm.a.red[16 + (tid >> 6)] = s2; }
                __syncthreads();
                if (tid == 0) {
                    double aa = 0, cc = 0;
                    for (int w = 0; w < 16; w++) { aa += sm.a.red[w]; cc += sm.a.red[16 + w]; }
                    parts[(1 - par)*NBLK + blk] = make_double2(aa, cc);
                }
                grid.sync();
            } else {
                // l=7: rev=0, x0 unchanged, y is new x1
                float z0 = 1.f / (1.f + expf(-x0v));
                float z1 = 1.f / (1.f + expf(-y));
                ((float2*)out)[b] = make_float2(z0, z1);
                out[2*BN_ + b] = sl + logf(z0 * (1.f - z0) + 1e-4f)
                                    + logf(z1 * (1.f - z1) + 1e-4f);
            }
        }
    }
}

extern "C" void kernel_launch(void* const* d_in, const int* in_sizes, int n_in,
                              void* d_out, int out_size, void* d_ws, size_t ws_size,
                              hipStream_t stream) {
    const float* x    = (const float*)d_in[0];
    const float* v1   = (const float*)d_in[1];
    const float* g1   = (const float*)d_in[2];
    // d_in[3] = b1: cancels exactly inside BN1, unused.
    const float* bn1g = (const float*)d_in[4];
    const float* bn1b = (const float*)d_in[5];
    const float* v2   = (const float*)d_in[6];
    const float* g2   = (const float*)d_in[7];
    const float* b2   = (const float*)d_in[8];
    const float* bn2g = (const float*)d_in[9];
    const float* bn2b = (const float*)d_in[10];
    const float* wf   = (const float*)d_in[11];
    const float* bf   = (const float*)d_in[12];
    float* ws  = (float*)d_ws;
    float* out = (float*)d_out;

    void* args[] = { (void*)&x, (void*)&v1, (void*)&g1, (void*)&bn1g, (void*)&bn1b,
                     (void*)&v2, (void*)&g2, (void*)&b2, (void*)&bn2g, (void*)&bn2b,
                     (void*)&wf, (void*)&bf, (void*)&ws, (void*)&out };
    hipLaunchCooperativeKernel((const void*)k_fused, dim3(NBLK), dim3(NTHR),
                               args, 0, stream);
}